// Round 5
// baseline (1098.149 us; speedup 1.0000x reference)
//
#include <hip/hip_runtime.h>
#include <hip/hip_bf16.h>

// Problem constants: B=128, T=512, V=50000, E=100, U=128, K=32
#define B_  128
#define T_  512
#define E_  100
#define U_  128
#define K_  32
#define G4  512   // 4*U

typedef _Float16 h2_t __attribute__((ext_vector_type(2)));
typedef __fp16   h2raw_t __attribute__((ext_vector_type(2)));

__device__ __forceinline__ h2_t pk2(float a, float b) {
    h2raw_t r = __builtin_amdgcn_cvt_pkrtz(a, b);
    union { h2raw_t r; h2_t h; } u; u.r = r; return u.h;
}
__device__ __forceinline__ int h2_as_int(h2_t v) { union { h2_t h; int i; } u; u.h = v; return u.i; }
__device__ __forceinline__ h2_t int_as_h2(int v) { union { h2_t h; int i; } u; u.i = v; return u.h; }

#if __has_builtin(__builtin_amdgcn_fdot2)
__device__ __forceinline__ float fdot2_f(h2_t a, h2_t b, float c) {
    return __builtin_amdgcn_fdot2(a, b, c, false);
}
#else
__device__ __forceinline__ float fdot2_f(h2_t a, h2_t b, float c) {
    return c + (float)a.x * (float)b.x + (float)a.y * (float)b.y;
}
#endif

// ---------------------------------------------------------------------------
// Kernel A: xk[row][j] = emb[tokens[row]] @ Wk + b   for both directions.
// TILE=32: 128 fma per 4 weight loads (was 64), half the Wk re-fetch.
// ---------------------------------------------------------------------------
__global__ __launch_bounds__(256, 1) void xk_kernel(
    const int* __restrict__ tokens, const float* __restrict__ emb,
    const float* __restrict__ Wk_f, const float* __restrict__ b_f,
    const float* __restrict__ Wk_b, const float* __restrict__ b_b,
    __hip_bfloat16* __restrict__ xk_f, __hip_bfloat16* __restrict__ xk_b)
{
    const int TILE = 32;
    __shared__ float x_lds[TILE][E_];   // 12.8 KB
    const int row0 = blockIdx.x * TILE;
    const int tid  = threadIdx.x;

    for (int idx = tid; idx < TILE * E_; idx += 256) {
        int r = idx / E_, e = idx - r * E_;
        int tok = tokens[row0 + r];
        x_lds[r][e] = emb[(long long)tok * E_ + e];
    }
    __syncthreads();

    float acc[TILE][4];
    #pragma unroll
    for (int r = 0; r < TILE; ++r)
        acc[r][0] = acc[r][1] = acc[r][2] = acc[r][3] = 0.f;

    const float* wf0 = Wk_f + tid;
    const float* wf1 = Wk_f + tid + 256;
    const float* wb0 = Wk_b + tid;
    const float* wb1 = Wk_b + tid + 256;

    for (int e = 0; e < E_; ++e) {
        float w0 = wf0[e * G4];
        float w1 = wf1[e * G4];
        float w2 = wb0[e * G4];
        float w3 = wb1[e * G4];
        #pragma unroll
        for (int r = 0; r < TILE; ++r) {
            float xv = x_lds[r][e];
            acc[r][0] = fmaf(xv, w0, acc[r][0]);
            acc[r][1] = fmaf(xv, w1, acc[r][1]);
            acc[r][2] = fmaf(xv, w2, acc[r][2]);
            acc[r][3] = fmaf(xv, w3, acc[r][3]);
        }
    }

    float bf0 = b_f[tid], bf1 = b_f[tid + 256];
    float bb0 = b_b[tid], bb1 = b_b[tid + 256];
    #pragma unroll
    for (int r = 0; r < TILE; ++r) {
        long long row = row0 + r;
        xk_f[row * G4 + tid]       = __float2bfloat16(acc[r][0] + bf0);
        xk_f[row * G4 + tid + 256] = __float2bfloat16(acc[r][1] + bf1);
        xk_b[row * G4 + tid]       = __float2bfloat16(acc[r][2] + bb0);
        xk_b[row * G4 + tid + 256] = __float2bfloat16(acc[r][3] + bb1);
    }
}

// ---------------------------------------------------------------------------
// Kernel B: LSTM, single-barrier step. 256 blocks = (dir,batch), 512 thr.
// Thread (part,q): 4 gate-cols {g*128+q}, u-slice [part*32,+32), w packed f16.
// Phase 2 replicated per wave: lanes 0..15 compute the wave's own 32 units
// (2/lane), producing next-step h pairs IN-LANE (no h LDS round-trip, no
// second barrier; partials double-buffered).
// ---------------------------------------------------------------------------
__device__ __forceinline__ float sigmoid_f(float x) {
    return 1.f / (1.f + __expf(-x));
}
__device__ __forceinline__ float tanh_f(float x) {
    float e = __expf(2.f * x);
    return 1.f - 2.f / (e + 1.f);
}

__global__ __launch_bounds__(512, 1) void lstm_kernel(
    const __hip_bfloat16* __restrict__ xk_f,
    const __hip_bfloat16* __restrict__ xk_b,
    const float* __restrict__ Wr_f, const float* __restrict__ Wr_b,
    __hip_bfloat16* __restrict__ h_buf)
{
    const int bid  = blockIdx.x;
    const int dir  = bid >> 7;
    const int b    = bid & 127;
    const int tid  = threadIdx.x;
    const int part = tid >> 7;       // 0..3 : u-slice [part*32, part*32+32)
    const int q    = tid & 127;      // gate-column within each gate
    const int lane = tid & 63;

    const float* Wr = dir ? Wr_b : Wr_f;
    const __hip_bfloat16* xk = dir ? xk_b : xk_f;

    // wp[g][i] packs Wr[part*32+2i][g*128+q], Wr[part*32+2i+1][g*128+q]
    h2_t wp[4][16];
    #pragma unroll
    for (int g = 0; g < 4; ++g)
        #pragma unroll
        for (int i = 0; i < 16; ++i)
            wp[g][i] = pk2(
                Wr[(part * 32 + 2 * i)     * G4 + g * 128 + q],
                Wr[(part * 32 + 2 * i + 1) * G4 + g * 128 + q]);

    // Double-buffered z-partials: [buf][gate][part][q]
    __shared__ __align__(8) float pl[2][4][4][U_];   // 16 KB

    // Per-lane state: units u0=part*32+2*(lane&15), u0+1 (replicated in
    // lane groups 16-31/32-47/48-63 — deterministic identical arithmetic).
    float c0 = 0.f, c1 = 0.f;
    int hp = 0;                       // packed f16 h pair (h=0 initially)

    const long long rowbase = (long long)b * T_;
    const int i16 = lane & 15;
    const int u0  = part * 32 + 2 * i16;

    int t0 = dir ? (T_ - 1) : 0;
    float xk_cur = __bfloat162float(xk[(rowbase + t0) * G4 + part * 128 + q]);

    for (int s = 0; s < T_; ++s) {
        const int t   = dir ? (T_ - 1 - s) : s;
        const int tn  = dir ? (t - 1) : (t + 1);
        const int buf = s & 1;

        // ---- phase 1: partial z for 4 gate-columns over own u-slice ----
        float a0 = (part == 0) ? xk_cur : 0.f;
        float a1 = (part == 1) ? xk_cur : 0.f;
        float a2 = (part == 2) ? xk_cur : 0.f;
        float a3 = (part == 3) ? xk_cur : 0.f;

        float xk_nxt = 0.f;
        if (s + 1 < T_)
            xk_nxt = __bfloat162float(xk[(rowbase + tn) * G4 + part * 128 + q]);

        #pragma unroll
        for (int i = 0; i < 16; ++i) {
            h2_t hh = int_as_h2(__builtin_amdgcn_readlane(hp, i));
            a0 = fdot2_f(hh, wp[0][i], a0);
            a1 = fdot2_f(hh, wp[1][i], a1);
            a2 = fdot2_f(hh, wp[2][i], a2);
            a3 = fdot2_f(hh, wp[3][i], a3);
        }

        pl[buf][0][part][q] = a0;
        pl[buf][1][part][q] = a1;
        pl[buf][2][part][q] = a2;
        pl[buf][3][part][q] = a3;
        __syncthreads();              // the ONLY barrier per step

        // ---- phase 2: every wave finishes its own 32 units ----
        float zi0 = 0.f, zi1 = 0.f, zf0 = 0.f, zf1 = 0.f;
        float zg0 = 0.f, zg1 = 0.f, zo0 = 0.f, zo1 = 0.f;
        #pragma unroll
        for (int p = 0; p < 4; ++p) {
            float2 v0 = *(const float2*)&pl[buf][0][p][u0];
            float2 v1 = *(const float2*)&pl[buf][1][p][u0];
            float2 v2 = *(const float2*)&pl[buf][2][p][u0];
            float2 v3 = *(const float2*)&pl[buf][3][p][u0];
            zi0 += v0.x; zi1 += v0.y;
            zf0 += v1.x; zf1 += v1.y;
            zg0 += v2.x; zg1 += v2.y;
            zo0 += v3.x; zo1 += v3.y;
        }

        c0 = sigmoid_f(zf0) * c0 + sigmoid_f(zi0) * tanh_f(zg0);
        c1 = sigmoid_f(zf1) * c1 + sigmoid_f(zi1) * tanh_f(zg1);
        float h0 = sigmoid_f(zo0) * tanh_f(c0);
        float h1 = sigmoid_f(zo1) * tanh_f(c1);
        hp = h2_as_int(pk2(h0, h1));  // next step's broadcast source, in-lane

        if ((tid & 64) == 0 && lane < 16) {
            __hip_bfloat16 hb0 = __float2bfloat16(h0);
            __hip_bfloat16 hb1 = __float2bfloat16(h1);
            unsigned int w = ((unsigned int)*(unsigned short*)&hb1 << 16)
                           |  (unsigned int)*(unsigned short*)&hb0;
            *(unsigned int*)(h_buf + (rowbase + t) * 256 + dir * U_ + u0) = w;
        }

        xk_cur = xk_nxt;
    }
}

// ---------------------------------------------------------------------------
// Kernel C: em = h_buf(65536x256 bf16) @ ck(256x32) + cb  -> f32 (65536x32).
// ---------------------------------------------------------------------------
__global__ __launch_bounds__(256) void em_kernel(
    const __hip_bfloat16* __restrict__ h_buf,
    const float* __restrict__ ck, const float* __restrict__ cb,
    float* __restrict__ em)
{
    const int tid  = threadIdx.x;
    const int part = tid >> 5;    // 0..7 -> u in [part*32, part*32+32)
    const int k    = tid & 31;

    float ckr[32];
    #pragma unroll
    for (int i = 0; i < 32; ++i)
        ckr[i] = ck[(part * 32 + i) * K_ + k];
    const float cbk = cb[k];

    __shared__ float h_l[8][256];
    __shared__ float part_l[8][8][K_];   // [row][part][k]

    const int r0 = blockIdx.x * 64;

    for (int round = 0; round < 8; ++round) {
        const int rbase = r0 + round * 8;
        #pragma unroll
        for (int j = 0; j < 8; ++j)
            h_l[j][tid] = __bfloat162float(h_buf[(long long)(rbase + j) * 256 + tid]);
        __syncthreads();

        #pragma unroll
        for (int j = 0; j < 8; ++j) {
            float p = 0.f;
            #pragma unroll
            for (int i = 0; i < 32; ++i)
                p = fmaf(h_l[j][part * 32 + i], ckr[i], p);
            part_l[j][part][k] = p;
        }
        __syncthreads();

        {
            int j2 = tid >> 5;
            float e = cbk;
            #pragma unroll
            for (int p = 0; p < 8; ++p) e += part_l[j2][p][k];
            em[(long long)(rbase + j2) * K_ + k] = e;
        }
        __syncthreads();
    }
}

// ---------------------------------------------------------------------------
// Kernel D: CRF logZ. 128 blocks x 1 wave, alpha/exp(trans) in registers.
// ---------------------------------------------------------------------------
#define PF_ 8
__global__ __launch_bounds__(64) void crf_kernel(
    const float* __restrict__ em,
    const float* __restrict__ trans,
    float* __restrict__ out)
{
    const int b    = blockIdx.x;
    const int lane = threadIdx.x;
    const int k    = lane & 31;
    const int half = lane >> 5;

    float etr[16];
    #pragma unroll
    for (int i = 0; i < 16; ++i)
        etr[i] = __expf(trans[(half * 16 + i) * K_ + k]);

    const float* em_b = em + (long long)b * T_ * K_;

    float ep[PF_];
    #pragma unroll
    for (int d = 0; d < PF_; ++d)
        ep[d] = em_b[d * K_ + k];

    float alpha = 0.f;
    for (int tb = 0; tb < T_; tb += PF_) {
        float en[PF_];
        if (tb + PF_ < T_) {
            #pragma unroll
            for (int d = 0; d < PF_; ++d)
                en[d] = em_b[(tb + PF_ + d) * K_ + k];
        } else {
            #pragma unroll
            for (int d = 0; d < PF_; ++d) en[d] = 0.f;
        }

        #pragma unroll
        for (int d = 0; d < PF_; ++d) {
            const int t = tb + d;
            if (t == 0) {
                alpha = ep[d];
            } else {
                float M = __shfl(alpha, 0, 64);
                float p = __expf(alpha - M);
                float acc = 0.f;
                #pragma unroll
                for (int i = 0; i < 16; ++i) {
                    float pv = __shfl(p, half * 16 + i, 64);
                    acc = fmaf(pv, etr[i], acc);
                }
                acc += __shfl_xor(acc, 32, 64);
                alpha = M + __logf(acc) + ep[d];
            }
        }
        #pragma unroll
        for (int d = 0; d < PF_; ++d) ep[d] = en[d];
    }

    float m = alpha;
    #pragma unroll
    for (int d = 1; d < 32; d <<= 1)
        m = fmaxf(m, __shfl_xor(m, d, 64));
    float s = __expf(alpha - m);
    #pragma unroll
    for (int d = 1; d < 32; d <<= 1)
        s += __shfl_xor(s, d, 64);
    if (lane == 0) out[b] = m + __logf(s);
}

// ---------------------------------------------------------------------------
extern "C" void kernel_launch(void* const* d_in, const int* in_sizes, int n_in,
                              void* d_out, int out_size, void* d_ws, size_t ws_size,
                              hipStream_t stream)
{
    const int*   tokens = (const int*)  d_in[0];
    const float* emb    = (const float*)d_in[1];
    const float* Wk_f   = (const float*)d_in[2];
    const float* Wr_f   = (const float*)d_in[3];
    const float* b_f    = (const float*)d_in[4];
    const float* Wk_b   = (const float*)d_in[5];
    const float* Wr_b   = (const float*)d_in[6];
    const float* b_b    = (const float*)d_in[7];
    const float* ck     = (const float*)d_in[8];
    const float* cb     = (const float*)d_in[9];
    const float* trans  = (const float*)d_in[10];
    float* out = (float*)d_out;

    const long long ROWS = (long long)B_ * T_;     // 65536
    __hip_bfloat16* xk_f  = (__hip_bfloat16*)d_ws;
    __hip_bfloat16* xk_b  = xk_f + ROWS * G4;
    __hip_bfloat16* h_buf = xk_b + ROWS * G4;
    float* em = (float*)d_ws;                      // alias, safe by ordering

    hipLaunchKernelGGL(xk_kernel, dim3((int)(ROWS / 32)), dim3(256), 0, stream,
                       tokens, emb, Wk_f, b_f, Wk_b, b_b, xk_f, xk_b);
    hipLaunchKernelGGL(lstm_kernel, dim3(256), dim3(512), 0, stream,
                       xk_f, xk_b, Wr_f, Wr_b, h_buf);
    hipLaunchKernelGGL(em_kernel, dim3((int)(ROWS / 64)), dim3(256), 0, stream,
                       h_buf, ck, cb, em);
    hipLaunchKernelGGL(crf_kernel, dim3(B_), dim3(64), 0, stream,
                       em, trans, out);
}

// Round 6
// 902.033 us; speedup vs baseline: 1.2174x; 1.2174x over previous
//
#include <hip/hip_runtime.h>
#include <hip/hip_bf16.h>

// Problem constants: B=128, T=512, V=50000, E=100, U=128, K=32
#define B_  128
#define T_  512
#define E_  100
#define U_  128
#define K_  32
#define G4  512   // 4*U

typedef _Float16 h2_t __attribute__((ext_vector_type(2)));
typedef __fp16   h2raw_t __attribute__((ext_vector_type(2)));

__device__ __forceinline__ h2_t pk2(float a, float b) {
    h2raw_t r = __builtin_amdgcn_cvt_pkrtz(a, b);
    union { h2raw_t r; h2_t h; } u; u.r = r; return u.h;
}
__device__ __forceinline__ int h2_as_int(h2_t v) { union { h2_t h; int i; } u; u.h = v; return u.i; }
__device__ __forceinline__ h2_t int_as_h2(int v) { union { h2_t h; int i; } u; u.i = v; return u.h; }

#if __has_builtin(__builtin_amdgcn_fdot2)
__device__ __forceinline__ float fdot2_f(h2_t a, h2_t b, float c) {
    return __builtin_amdgcn_fdot2(a, b, c, false);
}
#else
__device__ __forceinline__ float fdot2_f(h2_t a, h2_t b, float c) {
    return c + (float)a.x * (float)b.x + (float)a.y * (float)b.y;
}
#endif

// ---------------------------------------------------------------------------
// Kernel A: xk[row][j] = emb[tokens[row]] @ Wk + b   for both directions.
// ---------------------------------------------------------------------------
__global__ __launch_bounds__(256, 1) void xk_kernel(
    const int* __restrict__ tokens, const float* __restrict__ emb,
    const float* __restrict__ Wk_f, const float* __restrict__ b_f,
    const float* __restrict__ Wk_b, const float* __restrict__ b_b,
    __hip_bfloat16* __restrict__ xk_f, __hip_bfloat16* __restrict__ xk_b)
{
    const int TILE = 32;
    __shared__ float x_lds[TILE][E_];   // 12.8 KB
    const int row0 = blockIdx.x * TILE;
    const int tid  = threadIdx.x;

    for (int idx = tid; idx < TILE * E_; idx += 256) {
        int r = idx / E_, e = idx - r * E_;
        int tok = tokens[row0 + r];
        x_lds[r][e] = emb[(long long)tok * E_ + e];
    }
    __syncthreads();

    float acc[TILE][4];
    #pragma unroll
    for (int r = 0; r < TILE; ++r)
        acc[r][0] = acc[r][1] = acc[r][2] = acc[r][3] = 0.f;

    const float* wf0 = Wk_f + tid;
    const float* wf1 = Wk_f + tid + 256;
    const float* wb0 = Wk_b + tid;
    const float* wb1 = Wk_b + tid + 256;

    for (int e = 0; e < E_; ++e) {
        float w0 = wf0[e * G4];
        float w1 = wf1[e * G4];
        float w2 = wb0[e * G4];
        float w3 = wb1[e * G4];
        #pragma unroll
        for (int r = 0; r < TILE; ++r) {
            float xv = x_lds[r][e];
            acc[r][0] = fmaf(xv, w0, acc[r][0]);
            acc[r][1] = fmaf(xv, w1, acc[r][1]);
            acc[r][2] = fmaf(xv, w2, acc[r][2]);
            acc[r][3] = fmaf(xv, w3, acc[r][3]);
        }
    }

    float bf0 = b_f[tid], bf1 = b_f[tid + 256];
    float bb0 = b_b[tid], bb1 = b_b[tid + 256];
    #pragma unroll
    for (int r = 0; r < TILE; ++r) {
        long long row = row0 + r;
        xk_f[row * G4 + tid]       = __float2bfloat16(acc[r][0] + bf0);
        xk_f[row * G4 + tid + 256] = __float2bfloat16(acc[r][1] + bf1);
        xk_b[row * G4 + tid]       = __float2bfloat16(acc[r][2] + bb0);
        xk_b[row * G4 + tid + 256] = __float2bfloat16(acc[r][3] + bb1);
    }
}

// ---------------------------------------------------------------------------
// Kernel B: LSTM. 256 blocks = (dir,batch), 512 threads = 4 parts x 128 q.
// Phase 1 (R3 pattern): thread (part,q) -> 4 gate-cols {g*128+q} over u-slice
// [32part,+32), packed-f16 weights, readlane h broadcast, 64 dot2.
// Phase 2 distributed per-wave, 1 unit/lane: wave (part,h') finalizes units
// [32part,+32) (lane i -> unit 32part+(i&31), dup i/i+32 = free). z via one
// ds_read_b128 per gate (part dim rotated sum-invariantly for banks).
// h pairs re-packed IN-WAVE via 2 ds_bpermute -> next readlane. ONE barrier.
// ---------------------------------------------------------------------------
__device__ __forceinline__ float sigmoid_f(float x) {
    return 1.f / (1.f + __expf(-x));
}
__device__ __forceinline__ float tanh_f(float x) {
    float e = __expf(2.f * x);
    return 1.f - 2.f / (e + 1.f);
}

__global__ __launch_bounds__(512, 1) void lstm_kernel(
    const __hip_bfloat16* __restrict__ xk_f,
    const __hip_bfloat16* __restrict__ xk_b,
    const float* __restrict__ Wr_f, const float* __restrict__ Wr_b,
    __hip_bfloat16* __restrict__ h_buf)
{
    const int bid  = blockIdx.x;
    const int dir  = bid >> 7;
    const int b    = bid & 127;
    const int tid  = threadIdx.x;
    const int part = tid >> 7;       // 0..3 : u-slice [32part, 32part+32)
    const int q    = tid & 127;      // gate-column within each gate
    const int lane = tid & 63;
    const int wv   = tid >> 6;       // wave 0..7 (part = wv>>1)

    const float* Wr = dir ? Wr_b : Wr_f;
    const __hip_bfloat16* xk = dir ? xk_b : xk_f;

    // wp[g][i] packs Wr[32part+2i][g*128+q], Wr[32part+2i+1][g*128+q]
    h2_t wp[4][16];
    #pragma unroll
    for (int g = 0; g < 4; ++g)
        #pragma unroll
        for (int i = 0; i < 16; ++i)
            wp[g][i] = pk2(
                Wr[(part * 32 + 2 * i)     * G4 + g * 128 + q],
                Wr[(part * 32 + 2 * i + 1) * G4 + g * 128 + q]);

    // Double-buffered partials: [buf][gate][q][part-rotated]; b128-readable.
    __shared__ __align__(16) float pl[2][4][U_][4];   // 16 KB

    const int m   = (part << 5) + (lane & 31);   // unit this lane finalizes
    const int psw = (part + (q >> 3)) & 3;       // sum-invariant bank rotation
    float c = 0.f;
    int  hp = 0;                                  // packed f16 h pair

    const long long rowbase = (long long)b * T_;
    int t0 = dir ? (T_ - 1) : 0;
    float xk_cur = __bfloat162float(xk[(rowbase + t0) * G4 + tid]);

    for (int s = 0; s < T_; ++s) {
        const int t   = dir ? (T_ - 1 - s) : s;
        const int tn  = dir ? (t - 1) : (t + 1);
        const int buf = s & 1;

        // ---- phase 1 ----
        float a0 = (part == 0) ? xk_cur : 0.f;
        float a1 = (part == 1) ? xk_cur : 0.f;
        float a2 = (part == 2) ? xk_cur : 0.f;
        float a3 = (part == 3) ? xk_cur : 0.f;

        float xk_nxt = 0.f;
        if (s + 1 < T_)
            xk_nxt = __bfloat162float(xk[(rowbase + tn) * G4 + tid]);

        #pragma unroll
        for (int i = 0; i < 16; ++i) {
            h2_t hh = int_as_h2(__builtin_amdgcn_readlane(hp, i));
            a0 = fdot2_f(hh, wp[0][i], a0);
            a1 = fdot2_f(hh, wp[1][i], a1);
            a2 = fdot2_f(hh, wp[2][i], a2);
            a3 = fdot2_f(hh, wp[3][i], a3);
        }

        pl[buf][0][q][psw] = a0;
        pl[buf][1][q][psw] = a1;
        pl[buf][2][q][psw] = a2;
        pl[buf][3][q][psw] = a3;
        __syncthreads();              // the only barrier per step

        // ---- phase 2: this wave's own 32 units, 1 unit/lane (dup x2) ----
        float4 v0 = *(const float4*)&pl[buf][0][m][0];
        float4 v1 = *(const float4*)&pl[buf][1][m][0];
        float4 v2 = *(const float4*)&pl[buf][2][m][0];
        float4 v3 = *(const float4*)&pl[buf][3][m][0];
        float zi = (v0.x + v0.y) + (v0.z + v0.w);
        float zf = (v1.x + v1.y) + (v1.z + v1.w);
        float zg = (v2.x + v2.y) + (v2.z + v2.w);
        float zo = (v3.x + v3.y) + (v3.z + v3.w);

        c = sigmoid_f(zf) * c + sigmoid_f(zi) * tanh_f(zg);
        float h = sigmoid_f(zo) * tanh_f(c);

        if (((wv & 1) == 0) && lane < 32)
            h_buf[(rowbase + t) * 256 + dir * U_ + m] = __float2bfloat16(h);

        // repack pairs in-wave: lane j <- (h@lane 2j, h@lane 2j+1)
        int hi  = __float_as_int(h);
        int idx = (lane & 15) << 3;                       // byte idx of lane 2j
        int b0  = __builtin_amdgcn_ds_bpermute(idx,     hi);
        int b1  = __builtin_amdgcn_ds_bpermute(idx + 4, hi);
        hp = h2_as_int(pk2(__int_as_float(b0), __int_as_float(b1)));

        xk_cur = xk_nxt;
    }
}

// ---------------------------------------------------------------------------
// Kernel C: em = h_buf(65536x256 bf16) @ ck(256x32) + cb  -> f32 (65536x32).
// ---------------------------------------------------------------------------
__global__ __launch_bounds__(256) void em_kernel(
    const __hip_bfloat16* __restrict__ h_buf,
    const float* __restrict__ ck, const float* __restrict__ cb,
    float* __restrict__ em)
{
    const int tid  = threadIdx.x;
    const int part = tid >> 5;    // 0..7 -> u in [part*32, part*32+32)
    const int k    = tid & 31;

    float ckr[32];
    #pragma unroll
    for (int i = 0; i < 32; ++i)
        ckr[i] = ck[(part * 32 + i) * K_ + k];
    const float cbk = cb[k];

    __shared__ float h_l[8][256];
    __shared__ float part_l[8][8][K_];   // [row][part][k]

    const int r0 = blockIdx.x * 64;

    for (int round = 0; round < 8; ++round) {
        const int rbase = r0 + round * 8;
        #pragma unroll
        for (int j = 0; j < 8; ++j)
            h_l[j][tid] = __bfloat162float(h_buf[(long long)(rbase + j) * 256 + tid]);
        __syncthreads();

        #pragma unroll
        for (int j = 0; j < 8; ++j) {
            float p = 0.f;
            #pragma unroll
            for (int i = 0; i < 32; ++i)
                p = fmaf(h_l[j][part * 32 + i], ckr[i], p);
            part_l[j][part][k] = p;
        }
        __syncthreads();

        {
            int j2 = tid >> 5;
            float e = cbk;
            #pragma unroll
            for (int p = 0; p < 8; ++p) e += part_l[j2][p][k];
            em[(long long)(rbase + j2) * K_ + k] = e;
        }
        __syncthreads();
    }
}

// ---------------------------------------------------------------------------
// Kernel D: CRF logZ. 128 blocks x 1 wave, alpha/exp(trans) in registers.
// ---------------------------------------------------------------------------
#define PF_ 8
__global__ __launch_bounds__(64) void crf_kernel(
    const float* __restrict__ em,
    const float* __restrict__ trans,
    float* __restrict__ out)
{
    const int b    = blockIdx.x;
    const int lane = threadIdx.x;
    const int k    = lane & 31;
    const int half = lane >> 5;

    float etr[16];
    #pragma unroll
    for (int i = 0; i < 16; ++i)
        etr[i] = __expf(trans[(half * 16 + i) * K_ + k]);

    const float* em_b = em + (long long)b * T_ * K_;

    float ep[PF_];
    #pragma unroll
    for (int d = 0; d < PF_; ++d)
        ep[d] = em_b[d * K_ + k];

    float alpha = 0.f;
    for (int tb = 0; tb < T_; tb += PF_) {
        float en[PF_];
        if (tb + PF_ < T_) {
            #pragma unroll
            for (int d = 0; d < PF_; ++d)
                en[d] = em_b[(tb + PF_ + d) * K_ + k];
        } else {
            #pragma unroll
            for (int d = 0; d < PF_; ++d) en[d] = 0.f;
        }

        #pragma unroll
        for (int d = 0; d < PF_; ++d) {
            const int t = tb + d;
            if (t == 0) {
                alpha = ep[d];
            } else {
                float M = __shfl(alpha, 0, 64);
                float p = __expf(alpha - M);
                float acc = 0.f;
                #pragma unroll
                for (int i = 0; i < 16; ++i) {
                    float pv = __shfl(p, half * 16 + i, 64);
                    acc = fmaf(pv, etr[i], acc);
                }
                acc += __shfl_xor(acc, 32, 64);
                alpha = M + __logf(acc) + ep[d];
            }
        }
        #pragma unroll
        for (int d = 0; d < PF_; ++d) ep[d] = en[d];
    }

    float m = alpha;
    #pragma unroll
    for (int d = 1; d < 32; d <<= 1)
        m = fmaxf(m, __shfl_xor(m, d, 64));
    float s = __expf(alpha - m);
    #pragma unroll
    for (int d = 1; d < 32; d <<= 1)
        s += __shfl_xor(s, d, 64);
    if (lane == 0) out[b] = m + __logf(s);
}

// ---------------------------------------------------------------------------
extern "C" void kernel_launch(void* const* d_in, const int* in_sizes, int n_in,
                              void* d_out, int out_size, void* d_ws, size_t ws_size,
                              hipStream_t stream)
{
    const int*   tokens = (const int*)  d_in[0];
    const float* emb    = (const float*)d_in[1];
    const float* Wk_f   = (const float*)d_in[2];
    const float* Wr_f   = (const float*)d_in[3];
    const float* b_f    = (const float*)d_in[4];
    const float* Wk_b   = (const float*)d_in[5];
    const float* Wr_b   = (const float*)d_in[6];
    const float* b_b    = (const float*)d_in[7];
    const float* ck     = (const float*)d_in[8];
    const float* cb     = (const float*)d_in[9];
    const float* trans  = (const float*)d_in[10];
    float* out = (float*)d_out;

    const long long ROWS = (long long)B_ * T_;     // 65536
    __hip_bfloat16* xk_f  = (__hip_bfloat16*)d_ws;
    __hip_bfloat16* xk_b  = xk_f + ROWS * G4;
    __hip_bfloat16* h_buf = xk_b + ROWS * G4;
    float* em = (float*)d_ws;                      // alias, safe by ordering

    hipLaunchKernelGGL(xk_kernel, dim3((int)(ROWS / 32)), dim3(256), 0, stream,
                       tokens, emb, Wk_f, b_f, Wk_b, b_b, xk_f, xk_b);
    hipLaunchKernelGGL(lstm_kernel, dim3(256), dim3(512), 0, stream,
                       xk_f, xk_b, Wr_f, Wr_b, h_buf);
    hipLaunchKernelGGL(em_kernel, dim3((int)(ROWS / 64)), dim3(256), 0, stream,
                       h_buf, ck, cb, em);
    hipLaunchKernelGGL(crf_kernel, dim3(B_), dim3(64), 0, stream,
                       em, trans, out);
}

// Round 7
// 830.660 us; speedup vs baseline: 1.3220x; 1.0859x over previous
//
#include <hip/hip_runtime.h>
#include <hip/hip_bf16.h>

// Problem constants: B=128, T=512, V=50000, E=100, U=128, K=32
#define B_  128
#define T_  512
#define E_  100
#define U_  128
#define K_  32
#define G4  512   // 4*U
#define KP  128   // padded K for MFMA GEMM

typedef _Float16 h2_t __attribute__((ext_vector_type(2)));
typedef __fp16   h2raw_t __attribute__((ext_vector_type(2)));
typedef short    bf16x8 __attribute__((ext_vector_type(8)));
typedef float    f32x4  __attribute__((ext_vector_type(4)));

__device__ __forceinline__ h2_t pk2(float a, float b) {
    h2raw_t r = __builtin_amdgcn_cvt_pkrtz(a, b);
    union { h2raw_t r; h2_t h; } u; u.r = r; return u.h;
}
__device__ __forceinline__ int h2_as_int(h2_t v) { union { h2_t h; int i; } u; u.h = v; return u.i; }
__device__ __forceinline__ h2_t int_as_h2(int v) { union { h2_t h; int i; } u; u.i = v; return u.h; }

#if __has_builtin(__builtin_amdgcn_fdot2)
__device__ __forceinline__ float fdot2_f(h2_t a, h2_t b, float c) {
    return __builtin_amdgcn_fdot2(a, b, c, false);
}
#else
__device__ __forceinline__ float fdot2_f(h2_t a, h2_t b, float c) {
    return c + (float)a.x * (float)b.x + (float)a.y * (float)b.y;
}
#endif

__device__ __forceinline__ unsigned short bf16_bits(float v) {
    __hip_bfloat16 b = __float2bfloat16(v);
    union { __hip_bfloat16 b; unsigned short s; } u; u.b = b; return u.s;
}

// ---------------------------------------------------------------------------
// Kernel A0: pack Bb[n][k] (n-major, K padded to 128, bf16) from Wk_f|Wk_b.
// n<512 -> Wk_f col n ; n>=512 -> Wk_b col n-512. Rows k>=100 zero.
// ---------------------------------------------------------------------------
__global__ __launch_bounds__(128) void pack_b_kernel(
    const float* __restrict__ Wk_f, const float* __restrict__ Wk_b,
    __hip_bfloat16* __restrict__ Bb)
{
    const int n = blockIdx.x;     // 0..1023
    const int k = threadIdx.x;    // 0..127
    float v = 0.f;
    if (k < E_) v = (n < 512) ? Wk_f[k * 512 + n] : Wk_b[k * 512 + (n - 512)];
    Bb[n * KP + k] = __float2bfloat16(v);
}

// ---------------------------------------------------------------------------
// Kernel A: xk via MFMA. Block 256 thr (4 waves): tile M=32 rows, N=256 cols.
// grid = (65536/32, 1024/256). A staged bf16 in LDS (stride 136, 2-way free),
// B-frags register-resident (16/wave), epilogue via padded f32 LDS (+bias).
// Verified fragment layouts (m89/m120): A[m=lane&15][k=quad*8+j],
// B[k=quad*8+j][n=lane&15], D col=lane&15 row=quad*4+reg.
// ---------------------------------------------------------------------------
__global__ __launch_bounds__(256, 2) void xk_mfma_kernel(
    const int* __restrict__ tokens, const float* __restrict__ emb,
    const __hip_bfloat16* __restrict__ Bb,
    const float* __restrict__ b_f, const float* __restrict__ b_b,
    __hip_bfloat16* __restrict__ xk_f, __hip_bfloat16* __restrict__ xk_b)
{
    const int r0   = blockIdx.x * 32;
    const int n0   = blockIdx.y * 256;
    const int tid  = threadIdx.x;
    const int wv   = tid >> 6;      // wave 0..3 -> 64-col slice
    const int lane = tid & 63;
    const int quad = lane >> 4;
    const int l16  = lane & 15;

    __shared__ unsigned short A_lds[32][136];   // 8.7 KB, +8 pad
    __shared__ float C_lds[32][268];            // 34.3 KB, +12 pad (2-way free)

    // stage A: 32 rows of emb[tokens], bf16, K padded to 128
    for (int idx = tid; idx < 32 * KP; idx += 256) {
        int r = idx >> 7, k = idx & 127;
        float v = 0.f;
        if (k < E_) v = emb[(long long)tokens[r0 + r] * E_ + k];
        A_lds[r][k] = bf16_bits(v);
    }
    __syncthreads();

    // resident B-frags: bfr[nt][kc] for n-tile nt (16 cols), k-chunk kc (32)
    bf16x8 bfr[4][4];
    const unsigned short* Bu = (const unsigned short*)Bb;
    #pragma unroll
    for (int nt = 0; nt < 4; ++nt)
        #pragma unroll
        for (int kc = 0; kc < 4; ++kc)
            bfr[nt][kc] = *(const bf16x8*)(Bu +
                (n0 + wv * 64 + nt * 16 + l16) * KP + kc * 32 + quad * 8);

    f32x4 acc[2][4];
    #pragma unroll
    for (int mt = 0; mt < 2; ++mt)
        #pragma unroll
        for (int nt = 0; nt < 4; ++nt)
            acc[mt][nt] = (f32x4){0.f, 0.f, 0.f, 0.f};

    #pragma unroll
    for (int mt = 0; mt < 2; ++mt) {
        bf16x8 af[4];
        #pragma unroll
        for (int kc = 0; kc < 4; ++kc)
            af[kc] = *(const bf16x8*)&A_lds[mt * 16 + l16][kc * 32 + quad * 8];
        #pragma unroll
        for (int nt = 0; nt < 4; ++nt)
            #pragma unroll
            for (int kc = 0; kc < 4; ++kc)
                acc[mt][nt] = __builtin_amdgcn_mfma_f32_16x16x32_bf16(
                    af[kc], bfr[nt][kc], acc[mt][nt], 0, 0, 0);
    }

    // C to LDS: row = mt*16 + quad*4 + v, col = wv*64 + nt*16 + l16
    #pragma unroll
    for (int mt = 0; mt < 2; ++mt)
        #pragma unroll
        for (int nt = 0; nt < 4; ++nt)
            #pragma unroll
            for (int v = 0; v < 4; ++v)
                C_lds[mt * 16 + quad * 4 + v][wv * 64 + nt * 16 + l16] =
                    acc[mt][nt][v];
    __syncthreads();

    // epilogue: bias + bf16 pack + coalesced uint stores
    const float* bias = (n0 < 512) ? b_f : b_b;
    __hip_bfloat16* outp = (n0 < 512) ? xk_f : xk_b;
    const int nbase = n0 & 511;
    for (int idx = tid; idx < 32 * 128; idx += 256) {   // 128 col-pairs/row
        int r = idx >> 7, c = (idx & 127) * 2;
        float v0 = C_lds[r][c]     + bias[nbase + c];
        float v1 = C_lds[r][c + 1] + bias[nbase + c + 1];
        unsigned int w = ((unsigned int)bf16_bits(v1) << 16) | bf16_bits(v0);
        *(unsigned int*)(outp + (long long)(r0 + r) * G4 + nbase + c) = w;
    }
}

// ---------------------------------------------------------------------------
// Kernel B: LSTM — R3 structure (2 barriers, phase-2 on tid<128) with the
// rotated partial layout so phase-2 uses 4 ds_read_b128 instead of 16 b32.
// ---------------------------------------------------------------------------
__device__ __forceinline__ float sigmoid_f(float x) {
    return 1.f / (1.f + __expf(-x));
}
__device__ __forceinline__ float tanh_f(float x) {
    float e = __expf(2.f * x);
    return 1.f - 2.f / (e + 1.f);
}

__global__ __launch_bounds__(512, 1) void lstm_kernel(
    const __hip_bfloat16* __restrict__ xk_f,
    const __hip_bfloat16* __restrict__ xk_b,
    const float* __restrict__ Wr_f, const float* __restrict__ Wr_b,
    __hip_bfloat16* __restrict__ h_buf)
{
    const int bid  = blockIdx.x;
    const int dir  = bid >> 7;
    const int b    = bid & 127;
    const int tid  = threadIdx.x;
    const int part = tid >> 7;       // 0..3 : u-slice [32part, +32)
    const int q    = tid & 127;      // gate-column within each gate

    const float* Wr = dir ? Wr_b : Wr_f;
    const __hip_bfloat16* xk = dir ? xk_b : xk_f;

    // wp[g][i] packs Wr[32part+2i][g*128+q], Wr[32part+2i+1][g*128+q]
    h2_t wp[4][16];
    #pragma unroll
    for (int g = 0; g < 4; ++g)
        #pragma unroll
        for (int i = 0; i < 16; ++i)
            wp[g][i] = pk2(
                Wr[(part * 32 + 2 * i)     * G4 + g * 128 + q],
                Wr[(part * 32 + 2 * i + 1) * G4 + g * 128 + q]);

    __shared__ __align__(8)  float h_lds[U_];
    __shared__ __align__(16) float pl[4][U_][4];   // [gate][q][part-rotated]
    if (tid < U_) h_lds[tid] = 0.f;
    float c = 0.f;
    __syncthreads();

    const int psw = (part + (q >> 3)) & 3;         // sum-invariant rotation
    const long long rowbase = (long long)b * T_;
    int t0 = dir ? (T_ - 1) : 0;
    float xk_cur = __bfloat162float(xk[(rowbase + t0) * G4 + tid]);

    for (int s = 0; s < T_; ++s) {
        const int t  = dir ? (T_ - 1 - s) : s;
        const int tn = dir ? (t - 1) : (t + 1);

        float a0 = (part == 0) ? xk_cur : 0.f;
        float a1 = (part == 1) ? xk_cur : 0.f;
        float a2 = (part == 2) ? xk_cur : 0.f;
        float a3 = (part == 3) ? xk_cur : 0.f;

        float xk_nxt = 0.f;
        if (s + 1 < T_)
            xk_nxt = __bfloat162float(xk[(rowbase + tn) * G4 + tid]);

        float2 hv = ((const float2*)h_lds)[part * 16 + (tid & 15)];
        int hpi = h2_as_int(pk2(hv.x, hv.y));

        #pragma unroll
        for (int i = 0; i < 16; ++i) {
            h2_t hh = int_as_h2(__builtin_amdgcn_readlane(hpi, i));
            a0 = fdot2_f(hh, wp[0][i], a0);
            a1 = fdot2_f(hh, wp[1][i], a1);
            a2 = fdot2_f(hh, wp[2][i], a2);
            a3 = fdot2_f(hh, wp[3][i], a3);
        }

        pl[0][q][psw] = a0;
        pl[1][q][psw] = a1;
        pl[2][q][psw] = a2;
        pl[3][q][psw] = a3;
        __syncthreads();

        if (tid < U_) {
            float4 v0 = *(const float4*)&pl[0][tid][0];
            float4 v1 = *(const float4*)&pl[1][tid][0];
            float4 v2 = *(const float4*)&pl[2][tid][0];
            float4 v3 = *(const float4*)&pl[3][tid][0];
            float zi = (v0.x + v0.y) + (v0.z + v0.w);
            float zf = (v1.x + v1.y) + (v1.z + v1.w);
            float zg = (v2.x + v2.y) + (v2.z + v2.w);
            float zo = (v3.x + v3.y) + (v3.z + v3.w);
            c = sigmoid_f(zf) * c + sigmoid_f(zi) * tanh_f(zg);
            float h = sigmoid_f(zo) * tanh_f(c);
            h_lds[tid] = h;
            h_buf[(rowbase + t) * 256 + dir * U_ + tid] = __float2bfloat16(h);
        }
        __syncthreads();

        xk_cur = xk_nxt;
    }
}

// ---------------------------------------------------------------------------
// Kernel C: em = h_buf(65536x256 bf16) @ ck(256x32) + cb  -> f32 (65536x32).
// ---------------------------------------------------------------------------
__global__ __launch_bounds__(256) void em_kernel(
    const __hip_bfloat16* __restrict__ h_buf,
    const float* __restrict__ ck, const float* __restrict__ cb,
    float* __restrict__ em)
{
    const int tid  = threadIdx.x;
    const int part = tid >> 5;    // 0..7 -> u in [part*32, part*32+32)
    const int k    = tid & 31;

    float ckr[32];
    #pragma unroll
    for (int i = 0; i < 32; ++i)
        ckr[i] = ck[(part * 32 + i) * K_ + k];
    const float cbk = cb[k];

    __shared__ float h_l[8][256];
    __shared__ float part_l[8][8][K_];   // [row][part][k]

    const int r0 = blockIdx.x * 64;

    for (int round = 0; round < 8; ++round) {
        const int rbase = r0 + round * 8;
        #pragma unroll
        for (int j = 0; j < 8; ++j)
            h_l[j][tid] = __bfloat162float(h_buf[(long long)(rbase + j) * 256 + tid]);
        __syncthreads();

        #pragma unroll
        for (int j = 0; j < 8; ++j) {
            float p = 0.f;
            #pragma unroll
            for (int i = 0; i < 32; ++i)
                p = fmaf(h_l[j][part * 32 + i], ckr[i], p);
            part_l[j][part][k] = p;
        }
        __syncthreads();

        {
            int j2 = tid >> 5;
            float e = cbk;
            #pragma unroll
            for (int p = 0; p < 8; ++p) e += part_l[j2][p][k];
            em[(long long)(rbase + j2) * K_ + k] = e;
        }
        __syncthreads();
    }
}

// ---------------------------------------------------------------------------
// Kernel D: CRF logZ. 128 blocks x 1 wave, alpha/exp(trans) in registers.
// ---------------------------------------------------------------------------
#define PF_ 8
__global__ __launch_bounds__(64) void crf_kernel(
    const float* __restrict__ em,
    const float* __restrict__ trans,
    float* __restrict__ out)
{
    const int b    = blockIdx.x;
    const int lane = threadIdx.x;
    const int k    = lane & 31;
    const int half = lane >> 5;

    float etr[16];
    #pragma unroll
    for (int i = 0; i < 16; ++i)
        etr[i] = __expf(trans[(half * 16 + i) * K_ + k]);

    const float* em_b = em + (long long)b * T_ * K_;

    float ep[PF_];
    #pragma unroll
    for (int d = 0; d < PF_; ++d)
        ep[d] = em_b[d * K_ + k];

    float alpha = 0.f;
    for (int tb = 0; tb < T_; tb += PF_) {
        float en[PF_];
        if (tb + PF_ < T_) {
            #pragma unroll
            for (int d = 0; d < PF_; ++d)
                en[d] = em_b[(tb + PF_ + d) * K_ + k];
        } else {
            #pragma unroll
            for (int d = 0; d < PF_; ++d) en[d] = 0.f;
        }

        #pragma unroll
        for (int d = 0; d < PF_; ++d) {
            const int t = tb + d;
            if (t == 0) {
                alpha = ep[d];
            } else {
                float M = __shfl(alpha, 0, 64);
                float p = __expf(alpha - M);
                float acc = 0.f;
                #pragma unroll
                for (int i = 0; i < 16; ++i) {
                    float pv = __shfl(p, half * 16 + i, 64);
                    acc = fmaf(pv, etr[i], acc);
                }
                acc += __shfl_xor(acc, 32, 64);
                alpha = M + __logf(acc) + ep[d];
            }
        }
        #pragma unroll
        for (int d = 0; d < PF_; ++d) ep[d] = en[d];
    }

    float m = alpha;
    #pragma unroll
    for (int d = 1; d < 32; d <<= 1)
        m = fmaxf(m, __shfl_xor(m, d, 64));
    float s = __expf(alpha - m);
    #pragma unroll
    for (int d = 1; d < 32; d <<= 1)
        s += __shfl_xor(s, d, 64);
    if (lane == 0) out[b] = m + __logf(s);
}

// ---------------------------------------------------------------------------
extern "C" void kernel_launch(void* const* d_in, const int* in_sizes, int n_in,
                              void* d_out, int out_size, void* d_ws, size_t ws_size,
                              hipStream_t stream)
{
    const int*   tokens = (const int*)  d_in[0];
    const float* emb    = (const float*)d_in[1];
    const float* Wk_f   = (const float*)d_in[2];
    const float* Wr_f   = (const float*)d_in[3];
    const float* b_f    = (const float*)d_in[4];
    const float* Wk_b   = (const float*)d_in[5];
    const float* Wr_b   = (const float*)d_in[6];
    const float* b_b    = (const float*)d_in[7];
    const float* ck     = (const float*)d_in[8];
    const float* cb     = (const float*)d_in[9];
    const float* trans  = (const float*)d_in[10];
    float* out = (float*)d_out;

    // ws: xk_f (67.1MB) | xk_b (67.1MB) | h_buf (33.5MB).
    // Bb (256KB bf16) aliases h_buf head: written by pack_b, read by xk_mfma,
    // clobbered later by lstm (safe by ordering).
    // em (8.4MB f32) aliases xk_f, dead after lstm.
    const long long ROWS = (long long)B_ * T_;     // 65536
    __hip_bfloat16* xk_f  = (__hip_bfloat16*)d_ws;
    __hip_bfloat16* xk_b  = xk_f + ROWS * G4;
    __hip_bfloat16* h_buf = xk_b + ROWS * G4;
    __hip_bfloat16* Bb    = h_buf;                 // alias, safe by ordering
    float* em = (float*)d_ws;                      // alias, safe by ordering

    hipLaunchKernelGGL(pack_b_kernel, dim3(1024), dim3(128), 0, stream,
                       Wk_f, Wk_b, Bb);
    hipLaunchKernelGGL(xk_mfma_kernel, dim3((int)(ROWS / 32), 4), dim3(256), 0,
                       stream, tokens, emb, Bb, b_f, b_b, xk_f, xk_b);
    hipLaunchKernelGGL(lstm_kernel, dim3(256), dim3(512), 0, stream,
                       xk_f, xk_b, Wr_f, Wr_b, h_buf);
    hipLaunchKernelGGL(em_kernel, dim3((int)(ROWS / 64)), dim3(256), 0, stream,
                       h_buf, ck, cb, em);
    hipLaunchKernelGGL(crf_kernel, dim3(B_), dim3(64), 0, stream,
                       em, trans, out);
}

// Round 8
// 812.301 us; speedup vs baseline: 1.3519x; 1.0226x over previous
//
#include <hip/hip_runtime.h>
#include <hip/hip_bf16.h>

// Problem constants: B=128, T=512, V=50000, E=100, U=128, K=32
#define B_  128
#define T_  512
#define E_  100
#define U_  128
#define K_  32
#define G4  512   // 4*U
#define KP  128   // padded K for MFMA GEMM
#define GRP 8     // lstm time-group size

typedef _Float16 h2_t __attribute__((ext_vector_type(2)));
typedef __fp16   h2raw_t __attribute__((ext_vector_type(2)));
typedef short    bf16x8 __attribute__((ext_vector_type(8)));
typedef float    f32x4  __attribute__((ext_vector_type(4)));

__device__ __forceinline__ h2_t pk2(float a, float b) {
    h2raw_t r = __builtin_amdgcn_cvt_pkrtz(a, b);
    union { h2raw_t r; h2_t h; } u; u.r = r; return u.h;
}
__device__ __forceinline__ int h2_as_int(h2_t v) { union { h2_t h; int i; } u; u.h = v; return u.i; }
__device__ __forceinline__ h2_t int_as_h2(int v) { union { h2_t h; int i; } u; u.i = v; return u.h; }

#if __has_builtin(__builtin_amdgcn_fdot2)
__device__ __forceinline__ float fdot2_f(h2_t a, h2_t b, float c) {
    return __builtin_amdgcn_fdot2(a, b, c, false);
}
#else
__device__ __forceinline__ float fdot2_f(h2_t a, h2_t b, float c) {
    return c + (float)a.x * (float)b.x + (float)a.y * (float)b.y;
}
#endif

__device__ __forceinline__ unsigned short bf16_bits(float v) {
    __hip_bfloat16 b = __float2bfloat16(v);
    union { __hip_bfloat16 b; unsigned short s; } u; u.b = b; return u.s;
}

// ---------------------------------------------------------------------------
// Kernel A0: pack Bb[n][k] (n-major, K padded to 128, bf16) from Wk_f|Wk_b.
// ---------------------------------------------------------------------------
__global__ __launch_bounds__(128) void pack_b_kernel(
    const float* __restrict__ Wk_f, const float* __restrict__ Wk_b,
    __hip_bfloat16* __restrict__ Bb)
{
    const int n = blockIdx.x;     // 0..1023
    const int k = threadIdx.x;    // 0..127
    float v = 0.f;
    if (k < E_) v = (n < 512) ? Wk_f[k * 512 + n] : Wk_b[k * 512 + (n - 512)];
    Bb[n * KP + k] = __float2bfloat16(v);
}

// ---------------------------------------------------------------------------
// Kernel A: xk via MFMA. Block 256 thr (4 waves). B-frags loaded ONCE per
// block (16/wave) and amortized over 8 M-tiles of 32 rows.
// grid = (65536/256, 1024/256). Verified layouts (m89/m120).
// ---------------------------------------------------------------------------
__global__ __launch_bounds__(256, 2) void xk_mfma_kernel(
    const int* __restrict__ tokens, const float* __restrict__ emb,
    const __hip_bfloat16* __restrict__ Bb,
    const float* __restrict__ b_f, const float* __restrict__ b_b,
    __hip_bfloat16* __restrict__ xk_f, __hip_bfloat16* __restrict__ xk_b)
{
    const int n0   = blockIdx.y * 256;
    const int tid  = threadIdx.x;
    const int wv   = tid >> 6;      // wave 0..3 -> 64-col slice
    const int lane = tid & 63;
    const int quad = lane >> 4;
    const int l16  = lane & 15;

    __shared__ unsigned short A_lds[32][136];   // 8.7 KB, +8 pad
    __shared__ float C_lds[32][268];            // 34.3 KB

    // resident B-frags: bfr[nt][kc] for n-tile nt (16 cols), k-chunk kc (32)
    bf16x8 bfr[4][4];
    const unsigned short* Bu = (const unsigned short*)Bb;
    #pragma unroll
    for (int nt = 0; nt < 4; ++nt)
        #pragma unroll
        for (int kc = 0; kc < 4; ++kc)
            bfr[nt][kc] = *(const bf16x8*)(Bu +
                (n0 + wv * 64 + nt * 16 + l16) * KP + kc * 32 + quad * 8);

    const float* bias = (n0 < 512) ? b_f : b_b;
    __hip_bfloat16* outp = (n0 < 512) ? xk_f : xk_b;
    const int nbase = n0 & 511;

    for (int mt8 = 0; mt8 < 8; ++mt8) {
        const int r0 = (blockIdx.x * 8 + mt8) * 32;

        __syncthreads();   // A_lds/C_lds free from previous iteration

        for (int idx = tid; idx < 32 * KP; idx += 256) {
            int r = idx >> 7, k = idx & 127;
            float v = 0.f;
            if (k < E_) v = emb[(long long)tokens[r0 + r] * E_ + k];
            A_lds[r][k] = bf16_bits(v);
        }
        __syncthreads();

        f32x4 acc[2][4];
        #pragma unroll
        for (int mt = 0; mt < 2; ++mt)
            #pragma unroll
            for (int nt = 0; nt < 4; ++nt)
                acc[mt][nt] = (f32x4){0.f, 0.f, 0.f, 0.f};

        #pragma unroll
        for (int mt = 0; mt < 2; ++mt) {
            bf16x8 af[4];
            #pragma unroll
            for (int kc = 0; kc < 4; ++kc)
                af[kc] = *(const bf16x8*)&A_lds[mt * 16 + l16][kc * 32 + quad * 8];
            #pragma unroll
            for (int nt = 0; nt < 4; ++nt)
                #pragma unroll
                for (int kc = 0; kc < 4; ++kc)
                    acc[mt][nt] = __builtin_amdgcn_mfma_f32_16x16x32_bf16(
                        af[kc], bfr[nt][kc], acc[mt][nt], 0, 0, 0);
        }

        #pragma unroll
        for (int mt = 0; mt < 2; ++mt)
            #pragma unroll
            for (int nt = 0; nt < 4; ++nt)
                #pragma unroll
                for (int v = 0; v < 4; ++v)
                    C_lds[mt * 16 + quad * 4 + v][wv * 64 + nt * 16 + l16] =
                        acc[mt][nt][v];
        __syncthreads();

        for (int idx = tid; idx < 32 * 128; idx += 256) {
            int r = idx >> 7, c = (idx & 127) * 2;
            float v0 = C_lds[r][c]     + bias[nbase + c];
            float v1 = C_lds[r][c + 1] + bias[nbase + c + 1];
            unsigned int w = ((unsigned int)bf16_bits(v1) << 16) | bf16_bits(v0);
            *(unsigned int*)(outp + (long long)(r0 + r) * G4 + nbase + c) = w;
        }
    }
}

// ---------------------------------------------------------------------------
// Kernel B: LSTM — R6 structure, but ALL global traffic clustered at 8-step
// group boundaries so the per-barrier vmcnt(0) drain is paid once per group,
// not once per step. xk for group g+1 loaded at top of group g; h buffered
// in registers and stored at group end.
// ---------------------------------------------------------------------------
__device__ __forceinline__ float sigmoid_f(float x) {
    return 1.f / (1.f + __expf(-x));
}
__device__ __forceinline__ float tanh_f(float x) {
    float e = __expf(2.f * x);
    return 1.f - 2.f / (e + 1.f);
}

__global__ __launch_bounds__(512, 1) void lstm_kernel(
    const __hip_bfloat16* __restrict__ xk_f,
    const __hip_bfloat16* __restrict__ xk_b,
    const float* __restrict__ Wr_f, const float* __restrict__ Wr_b,
    __hip_bfloat16* __restrict__ h_buf)
{
    const int bid  = blockIdx.x;
    const int dir  = bid >> 7;
    const int b    = bid & 127;
    const int tid  = threadIdx.x;
    const int part = tid >> 7;       // 0..3 : u-slice [32part, +32)
    const int q    = tid & 127;      // gate-column within each gate

    const float* Wr = dir ? Wr_b : Wr_f;
    const __hip_bfloat16* xk = dir ? xk_b : xk_f;

    h2_t wp[4][16];
    #pragma unroll
    for (int g = 0; g < 4; ++g)
        #pragma unroll
        for (int i = 0; i < 16; ++i)
            wp[g][i] = pk2(
                Wr[(part * 32 + 2 * i)     * G4 + g * 128 + q],
                Wr[(part * 32 + 2 * i + 1) * G4 + g * 128 + q]);

    __shared__ __align__(8)  float h_lds[U_];
    __shared__ __align__(16) float pl[4][U_][4];   // [gate][q][part-rotated]
    if (tid < U_) h_lds[tid] = 0.f;
    float c = 0.f;
    __syncthreads();

    const int psw = (part + (q >> 3)) & 3;         // sum-invariant rotation
    const long long rowbase = (long long)b * T_;
    const __hip_bfloat16* xkp = xk + rowbase * G4 + tid;

    float xk_cur[GRP];
    #pragma unroll
    for (int d = 0; d < GRP; ++d) {
        int t = dir ? (T_ - 1 - d) : d;
        xk_cur[d] = __bfloat162float(xkp[t * G4]);
    }
    float h_st[GRP];
    #pragma unroll
    for (int d = 0; d < GRP; ++d) h_st[d] = 0.f;

    for (int g = 0; g < T_ / GRP; ++g) {
        // prefetch next group's xk (clustered vmem issue)
        float xk_nxt[GRP];
        #pragma unroll
        for (int d = 0; d < GRP; ++d) xk_nxt[d] = 0.f;
        if (g + 1 < T_ / GRP) {
            #pragma unroll
            for (int d = 0; d < GRP; ++d) {
                int s = (g + 1) * GRP + d;
                int t = dir ? (T_ - 1 - s) : s;
                xk_nxt[d] = __bfloat162float(xkp[t * G4]);
            }
        }

        #pragma unroll
        for (int d = 0; d < GRP; ++d) {
            float a0 = (part == 0) ? xk_cur[d] : 0.f;
            float a1 = (part == 1) ? xk_cur[d] : 0.f;
            float a2 = (part == 2) ? xk_cur[d] : 0.f;
            float a3 = (part == 3) ? xk_cur[d] : 0.f;

            float2 hv = ((const float2*)h_lds)[part * 16 + (tid & 15)];
            int hpi = h2_as_int(pk2(hv.x, hv.y));

            #pragma unroll
            for (int i = 0; i < 16; ++i) {
                h2_t hh = int_as_h2(__builtin_amdgcn_readlane(hpi, i));
                a0 = fdot2_f(hh, wp[0][i], a0);
                a1 = fdot2_f(hh, wp[1][i], a1);
                a2 = fdot2_f(hh, wp[2][i], a2);
                a3 = fdot2_f(hh, wp[3][i], a3);
            }

            pl[0][q][psw] = a0;
            pl[1][q][psw] = a1;
            pl[2][q][psw] = a2;
            pl[3][q][psw] = a3;
            __syncthreads();

            if (tid < U_) {
                float4 v0 = *(const float4*)&pl[0][tid][0];
                float4 v1 = *(const float4*)&pl[1][tid][0];
                float4 v2 = *(const float4*)&pl[2][tid][0];
                float4 v3 = *(const float4*)&pl[3][tid][0];
                float zi = (v0.x + v0.y) + (v0.z + v0.w);
                float zf = (v1.x + v1.y) + (v1.z + v1.w);
                float zg = (v2.x + v2.y) + (v2.z + v2.w);
                float zo = (v3.x + v3.y) + (v3.z + v3.w);
                c = sigmoid_f(zf) * c + sigmoid_f(zi) * tanh_f(zg);
                float h = sigmoid_f(zo) * tanh_f(c);
                h_lds[tid] = h;
                h_st[d] = h;
            }
            __syncthreads();
        }

        // clustered h stores for the whole group
        if (tid < U_) {
            #pragma unroll
            for (int d = 0; d < GRP; ++d) {
                int s = g * GRP + d;
                int t = dir ? (T_ - 1 - s) : s;
                h_buf[(rowbase + t) * 256 + dir * U_ + tid] =
                    __float2bfloat16(h_st[d]);
            }
        }

        #pragma unroll
        for (int d = 0; d < GRP; ++d) xk_cur[d] = xk_nxt[d];
    }
}

// ---------------------------------------------------------------------------
// Kernel C: em = h_buf(65536x256 bf16) @ ck(256x32) + cb  -> f32 (65536x32).
// ---------------------------------------------------------------------------
__global__ __launch_bounds__(256) void em_kernel(
    const __hip_bfloat16* __restrict__ h_buf,
    const float* __restrict__ ck, const float* __restrict__ cb,
    float* __restrict__ em)
{
    const int tid  = threadIdx.x;
    const int part = tid >> 5;    // 0..7 -> u in [part*32, part*32+32)
    const int k    = tid & 31;

    float ckr[32];
    #pragma unroll
    for (int i = 0; i < 32; ++i)
        ckr[i] = ck[(part * 32 + i) * K_ + k];
    const float cbk = cb[k];

    __shared__ float h_l[8][256];
    __shared__ float part_l[8][8][K_];   // [row][part][k]

    const int r0 = blockIdx.x * 64;

    for (int round = 0; round < 8; ++round) {
        const int rbase = r0 + round * 8;
        #pragma unroll
        for (int j = 0; j < 8; ++j)
            h_l[j][tid] = __bfloat162float(h_buf[(long long)(rbase + j) * 256 + tid]);
        __syncthreads();

        #pragma unroll
        for (int j = 0; j < 8; ++j) {
            float p = 0.f;
            #pragma unroll
            for (int i = 0; i < 32; ++i)
                p = fmaf(h_l[j][part * 32 + i], ckr[i], p);
            part_l[j][part][k] = p;
        }
        __syncthreads();

        {
            int j2 = tid >> 5;
            float e = cbk;
            #pragma unroll
            for (int p = 0; p < 8; ++p) e += part_l[j2][p][k];
            em[(long long)(rbase + j2) * K_ + k] = e;
        }
        __syncthreads();
    }
}

// ---------------------------------------------------------------------------
// Kernel D: CRF logZ. 128 blocks x 1 wave, alpha/exp(trans) in registers.
// ---------------------------------------------------------------------------
#define PF_ 8
__global__ __launch_bounds__(64) void crf_kernel(
    const float* __restrict__ em,
    const float* __restrict__ trans,
    float* __restrict__ out)
{
    const int b    = blockIdx.x;
    const int lane = threadIdx.x;
    const int k    = lane & 31;
    const int half = lane >> 5;

    float etr[16];
    #pragma unroll
    for (int i = 0; i < 16; ++i)
        etr[i] = __expf(trans[(half * 16 + i) * K_ + k]);

    const float* em_b = em + (long long)b * T_ * K_;

    float ep[PF_];
    #pragma unroll
    for (int d = 0; d < PF_; ++d)
        ep[d] = em_b[d * K_ + k];

    float alpha = 0.f;
    for (int tb = 0; tb < T_; tb += PF_) {
        float en[PF_];
        if (tb + PF_ < T_) {
            #pragma unroll
            for (int d = 0; d < PF_; ++d)
                en[d] = em_b[(tb + PF_ + d) * K_ + k];
        } else {
            #pragma unroll
            for (int d = 0; d < PF_; ++d) en[d] = 0.f;
        }

        #pragma unroll
        for (int d = 0; d < PF_; ++d) {
            const int t = tb + d;
            if (t == 0) {
                alpha = ep[d];
            } else {
                float M = __shfl(alpha, 0, 64);
                float p = __expf(alpha - M);
                float acc = 0.f;
                #pragma unroll
                for (int i = 0; i < 16; ++i) {
                    float pv = __shfl(p, half * 16 + i, 64);
                    acc = fmaf(pv, etr[i], acc);
                }
                acc += __shfl_xor(acc, 32, 64);
                alpha = M + __logf(acc) + ep[d];
            }
        }
        #pragma unroll
        for (int d = 0; d < PF_; ++d) ep[d] = en[d];
    }

    float m = alpha;
    #pragma unroll
    for (int d = 1; d < 32; d <<= 1)
        m = fmaxf(m, __shfl_xor(m, d, 64));
    float s = __expf(alpha - m);
    #pragma unroll
    for (int d = 1; d < 32; d <<= 1)
        s += __shfl_xor(s, d, 64);
    if (lane == 0) out[b] = m + __logf(s);
}

// ---------------------------------------------------------------------------
extern "C" void kernel_launch(void* const* d_in, const int* in_sizes, int n_in,
                              void* d_out, int out_size, void* d_ws, size_t ws_size,
                              hipStream_t stream)
{
    const int*   tokens = (const int*)  d_in[0];
    const float* emb    = (const float*)d_in[1];
    const float* Wk_f   = (const float*)d_in[2];
    const float* Wr_f   = (const float*)d_in[3];
    const float* b_f    = (const float*)d_in[4];
    const float* Wk_b   = (const float*)d_in[5];
    const float* Wr_b   = (const float*)d_in[6];
    const float* b_b    = (const float*)d_in[7];
    const float* ck     = (const float*)d_in[8];
    const float* cb     = (const float*)d_in[9];
    const float* trans  = (const float*)d_in[10];
    float* out = (float*)d_out;

    const long long ROWS = (long long)B_ * T_;     // 65536
    __hip_bfloat16* xk_f  = (__hip_bfloat16*)d_ws;
    __hip_bfloat16* xk_b  = xk_f + ROWS * G4;
    __hip_bfloat16* h_buf = xk_b + ROWS * G4;
    __hip_bfloat16* Bb    = h_buf;                 // alias, safe by ordering
    float* em = (float*)d_ws;                      // alias, safe by ordering

    hipLaunchKernelGGL(pack_b_kernel, dim3(1024), dim3(128), 0, stream,
                       Wk_f, Wk_b, Bb);
    hipLaunchKernelGGL(xk_mfma_kernel, dim3((int)(ROWS / 256), 4), dim3(256), 0,
                       stream, tokens, emb, Bb, b_f, b_b, xk_f, xk_b);
    hipLaunchKernelGGL(lstm_kernel, dim3(256), dim3(512), 0, stream,
                       xk_f, xk_b, Wr_f, Wr_b, h_buf);
    hipLaunchKernelGGL(em_kernel, dim3((int)(ROWS / 64)), dim3(256), 0, stream,
                       h_buf, ck, cb, em);
    hipLaunchKernelGGL(crf_kernel, dim3(B_), dim3(64), 0, stream,
                       em, trans, out);
}